// Round 22
// baseline (86.731 us; speedup 1.0000x reference)
//
#include <hip/hip_runtime.h>
#include <hip/hip_bf16.h>

#define B_ 16384
#define F_ 128
#define D_ 256
#define A_ 256
#define T_ 64
#define DECAY_ 0.9f
#define SCALE2 2.885390081777927f   // 2*log2(e)
#define L2E    1.4426950408889634f  // log2(e)

typedef __attribute__((ext_vector_type(8))) __bf16 bf16x8;
typedef __attribute__((ext_vector_type(4))) float f32x4;

#if __has_builtin(__builtin_amdgcn_exp2f)
#define EXP2(x) __builtin_amdgcn_exp2f(x)
#else
#define EXP2(x) exp2f(x)
#endif
#define RCP(x) __builtin_amdgcn_rcpf(x)

__device__ __forceinline__ float tanh2(float x) {
    float e = EXP2(SCALE2 * x);
    return 1.0f - 2.0f * RCP(e + 1.0f);
}
__device__ __forceinline__ float sigmoid2(float x) {
    float e = EXP2(-L2E * x);
    return RCP(1.0f + e);
}
__device__ __forceinline__ bool get_mask(const void* mp, int mflag, int row) {
    if (mflag) return ((const unsigned char*)mp)[row] != 0;
    return ((const int*)mp)[row] != 0;
}
__device__ __forceinline__ unsigned short bfbits(float f) {
    __bf16 h = (__bf16)f;
    return __builtin_bit_cast(unsigned short, h);
}

// ---- merged front kernel: blocks 0-351 convert weights, 352 = mask probe, 353-416 = prep ----
// prep: histT[d][t] = bf16(tanh(tokens)) [256][64]; etp = bf16(exp2(SCALE2*tok_proj)) packed
// etp layout: element (a,t) at (a>>2)*256 + t*4 + (a&3)
__global__ __launch_bounds__(256) void convert_prep(
    const float* Wih, const float* Whh, const float* Wc,
    __bf16* Wihb, __bf16* Whhb, __bf16* Wcb,
    const unsigned int* mword, int* flag,
    const float* tokens, const float* Wh, const float* bh,
    __bf16* histT, __bf16* etp)
{
    __shared__ float hrow[D_];
    const int n1 = 768 * 128, n2 = n1 + 768 * 256, n3 = n2 + 256 * 256;
    int bid = blockIdx.x;
    int tid = threadIdx.x;

    if (bid >= 353) {               // ---- prep path: t = bid - 353 ----
        int t = bid - 353;
        float hv = tanh2(tokens[t * D_ + tid]);
        hrow[tid] = hv;
        histT[tid * T_ + t] = (__bf16)hv;   // transposed for MFMA B-frag
        __syncthreads();
        float acc = bh[tid];
        const float* wr = &Wh[tid * D_];
        for (int d = 0; d < D_; d++) acc += hrow[d] * wr[d];
        etp[(tid >> 2) * 256 + t * 4 + (tid & 3)] = (__bf16)EXP2(acc * SCALE2);
        return;
    }
    if (bid == 352) {               // ---- mask probe: packed bools -> some 4B word >1 ----
        __shared__ int f;
        if (tid == 0) f = 0;
        __syncthreads();
        int any = 0;
        for (int i = tid; i < B_ / 4; i += 256) any |= (mword[i] > 1u) ? 1 : 0;
        if (any) atomicOr(&f, 1);
        __syncthreads();
        if (tid == 0) flag[0] = f;
        return;
    }
    int i = (bid * 256 + tid) * 4;  // ---- weight conversion ----
    if (i < n1) {
#pragma unroll
        for (int j = 0; j < 4; ++j) Wihb[i + j] = (__bf16)Wih[i + j];
    } else if (i < n2) {
        int k = i - n1;
#pragma unroll
        for (int j = 0; j < 4; ++j) Whhb[k + j] = (__bf16)Whh[k + j];
    } else if (i < n3) {
        int k = i - n2;
#pragma unroll
        for (int j = 0; j < 4; ++j) Wcb[k + j] = (__bf16)Wc[k + j];
    }
}

// ---- fused gru+attn: 64 rows/block, 1024 thr. Phases:
//  1 stage -> 2 gates MFMA -> 3 gate epilogue (hn overlay, hout) -> 4 ctx MFMA
//  -> 5 ec=exp2(ctx~) f32 into LDS (Xs reused) -> 6 score (attn11 loop) -> 7 softmax
//  -> 8 emb MFMA + masked accum/out.
#define XS 392   // shorts/row: 384 + 8 pad (f[0:128] | h->hn[128:384])
__global__ __launch_bounds__(1024) void gru_attn(
    const float* __restrict__ features, const float* __restrict__ h,
    const void* maskp, const int* __restrict__ mflagp,
    const __bf16* __restrict__ Wihb, const __bf16* __restrict__ Whhb, const __bf16* __restrict__ Wcb,
    const float* __restrict__ b_ih, const float* __restrict__ b_hh, const float* __restrict__ bcp,
    const unsigned short* __restrict__ etp, const __bf16* __restrict__ histT,
    const float* __restrict__ v, const float* __restrict__ accum,
    float* __restrict__ hout, float* __restrict__ out_emb)
{
    __shared__ __align__(16) unsigned char smem[64 * 256 * 4];  // 64KB: Xs (50KB) then ec f32
    __bf16* Xs  = (__bf16*)smem;          // [64][XS]
    float*  ecl = (float*)smem;           // [64][256], valid after phase 5
    __shared__ float vs[A_];              // 1KB
    __shared__ __bf16 wgtb[64 * 72];      // 9KB softmax weights
    int tid = threadIdx.x;
    int b0 = blockIdx.x * 64;
    int wv = tid >> 6, lane = tid & 63;   // wv in [0,16)
    int lan15 = lane & 15, kg = lane >> 4;
    int klo = kg * 8;
    int d = wv * 16 + lan15;              // gru: this thread's gate column
    int mflag = mflagp[0];

    // ---- phase 1: stage features (64x128) + h (64x256) bf16; stage v ----
#pragma unroll
    for (int it = 0; it < 2; ++it) {
        int idx = (it * 1024 + tid) * 4;
        int r = idx >> 7, c = idx & 127;
        float4 vv = *(const float4*)&features[(size_t)(b0 + r) * F_ + c];
        ushort4 w = { bfbits(vv.x), bfbits(vv.y), bfbits(vv.z), bfbits(vv.w) };
        *reinterpret_cast<ushort4*>(&Xs[r * XS + c]) = w;
    }
#pragma unroll
    for (int it = 0; it < 4; ++it) {
        int idx = (it * 1024 + tid) * 4;
        int r = idx >> 8, c = idx & 255;
        float4 vv = *(const float4*)&h[(size_t)(b0 + r) * D_ + c];
        ushort4 w = { bfbits(vv.x), bfbits(vv.y), bfbits(vv.z), bfbits(vv.w) };
        *reinterpret_cast<ushort4*>(&Xs[r * XS + 128 + c]) = w;
    }
    if (tid < 64) ((float4*)vs)[tid] = ((const float4*)v)[tid];
    float brv = b_ih[d] + b_hh[d];
    float bzv = b_ih[256 + d] + b_hh[256 + d];
    float biv = b_ih[512 + d];
    float bhv = b_hh[512 + d];
    float bcv = bcp[d];
    __syncthreads();

    // ---- phase 2: gates MFMA ----
    f32x4 ar[4] = {}, az[4] = {}, ai[4] = {}, ah[4] = {};
#pragma unroll
    for (int kb = 0; kb < 4; ++kb) {
        bf16x8 a[4];
#pragma unroll
        for (int rf = 0; rf < 4; ++rf)
            a[rf] = *reinterpret_cast<const bf16x8*>(&Xs[(rf * 16 + lan15) * XS + kb * 32 + klo]);
        const __bf16* p = Wihb + (size_t)d * F_ + kb * 32 + klo;
        bf16x8 br = *reinterpret_cast<const bf16x8*>(p);
        bf16x8 bz = *reinterpret_cast<const bf16x8*>(p + 256 * F_);
        bf16x8 bn = *reinterpret_cast<const bf16x8*>(p + 512 * F_);
#pragma unroll
        for (int rf = 0; rf < 4; ++rf) {
            ar[rf] = __builtin_amdgcn_mfma_f32_16x16x32_bf16(a[rf], br, ar[rf], 0, 0, 0);
            az[rf] = __builtin_amdgcn_mfma_f32_16x16x32_bf16(a[rf], bz, az[rf], 0, 0, 0);
            ai[rf] = __builtin_amdgcn_mfma_f32_16x16x32_bf16(a[rf], bn, ai[rf], 0, 0, 0);
        }
    }
#pragma unroll
    for (int kb = 0; kb < 8; ++kb) {
        bf16x8 a[4];
#pragma unroll
        for (int rf = 0; rf < 4; ++rf)
            a[rf] = *reinterpret_cast<const bf16x8*>(&Xs[(rf * 16 + lan15) * XS + 128 + kb * 32 + klo]);
        const __bf16* p = Whhb + (size_t)d * D_ + kb * 32 + klo;
        bf16x8 br = *reinterpret_cast<const bf16x8*>(p);
        bf16x8 bz = *reinterpret_cast<const bf16x8*>(p + 256 * D_);
        bf16x8 bn = *reinterpret_cast<const bf16x8*>(p + 512 * D_);
#pragma unroll
        for (int rf = 0; rf < 4; ++rf) {
            ar[rf] = __builtin_amdgcn_mfma_f32_16x16x32_bf16(a[rf], br, ar[rf], 0, 0, 0);
            az[rf] = __builtin_amdgcn_mfma_f32_16x16x32_bf16(a[rf], bz, az[rf], 0, 0, 0);
            ah[rf] = __builtin_amdgcn_mfma_f32_16x16x32_bf16(a[rf], bn, ah[rf], 0, 0, 0);
        }
    }
    __syncthreads();   // all waves done reading old h before any overlay write

    // ---- phase 3: gate epilogue (hn overlay in place, masked hout) ----
#pragma unroll
    for (int rf = 0; rf < 4; ++rf) {
#pragma unroll
        for (int rg = 0; rg < 4; ++rg) {
            int row = rf * 16 + kg * 4 + rg;
            int grow = b0 + row;
            float hv = (float)Xs[row * XS + 128 + d];
            float rv = sigmoid2(ar[rf][rg] + brv);
            float zv = sigmoid2(az[rf][rg] + bzv);
            float nv = tanh2(ai[rf][rg] + biv + rv * (ah[rf][rg] + bhv));
            float hn = (1.0f - zv) * nv + zv * hv;
            Xs[row * XS + 128 + d] = (__bf16)hn;   // owner-exclusive cell
            bool m = get_mask(maskp, mflag, grow);
            hout[(size_t)grow * D_ + d] = m ? hn : hv;
        }
    }
    __syncthreads();

    // ---- phase 4: ctx MFMA (reads Hn from Xs) ----
    f32x4 ac[4] = {};
#pragma unroll
    for (int kb = 0; kb < 8; ++kb) {
        bf16x8 b = *reinterpret_cast<const bf16x8*>(&Wcb[(size_t)d * D_ + kb * 32 + klo]);
#pragma unroll
        for (int rf = 0; rf < 4; ++rf) {
            bf16x8 a = *reinterpret_cast<const bf16x8*>(&Xs[(rf * 16 + lan15) * XS + 128 + kb * 32 + klo]);
            ac[rf] = __builtin_amdgcn_mfma_f32_16x16x32_bf16(a, b, ac[rf], 0, 0, 0);
        }
    }
    __syncthreads();   // ALL Hn reads complete before ecl clobbers Xs

    // ---- phase 5: ec = exp2(ctx~) f32 into LDS (owner cells) ----
#pragma unroll
    for (int rf = 0; rf < 4; ++rf) {
#pragma unroll
        for (int rg = 0; rg < 4; ++rg) {
            int row = rf * 16 + kg * 4 + rg;
            ecl[row * 256 + d] = EXP2((ac[rf][rg] + bcv) * SCALE2);
        }
    }
    __syncthreads();   // ec visible to all waves

    // ---- phase 6: score loop (attn11): wave wv owns rows wv*4..wv*4+3, lane = t ----
    const float* ecb = ecl + (size_t)(wv * 4) * 256;
    float p0 = 0.f, p1 = 0.f, p2 = 0.f, p3 = 0.f;
#pragma unroll 4
    for (int ch = 0; ch < 32; ++ch) {
        int a0 = ch * 8;
        const unsigned short* ep = etp + (a0 >> 2) * 256 + lane * 4;
        uint2 q0 = *(const uint2*)ep;            // et for a0..a0+3 at this lane's t
        uint2 q1 = *(const uint2*)(ep + 256);    // a0+4..a0+7
        float4 vA = *(const float4*)&vs[a0];
        float4 vB = *(const float4*)&vs[a0 + 4];
        float ecr[4][8];
#pragma unroll
        for (int r = 0; r < 4; ++r) {
            float4 ca = *(const float4*)&ecb[r * 256 + a0];
            float4 cb = *(const float4*)&ecb[r * 256 + a0 + 4];
            ecr[r][0] = ca.x; ecr[r][1] = ca.y; ecr[r][2] = ca.z; ecr[r][3] = ca.w;
            ecr[r][4] = cb.x; ecr[r][5] = cb.y; ecr[r][6] = cb.z; ecr[r][7] = cb.w;
        }
        float et[8];
        et[0] = __builtin_bit_cast(float, q0.x << 16);
        et[1] = __builtin_bit_cast(float, q0.x & 0xffff0000u);
        et[2] = __builtin_bit_cast(float, q0.y << 16);
        et[3] = __builtin_bit_cast(float, q0.y & 0xffff0000u);
        et[4] = __builtin_bit_cast(float, q1.x << 16);
        et[5] = __builtin_bit_cast(float, q1.x & 0xffff0000u);
        et[6] = __builtin_bit_cast(float, q1.y << 16);
        et[7] = __builtin_bit_cast(float, q1.y & 0xffff0000u);
        float vv[8];
        vv[0] = vA.x; vv[1] = vA.y; vv[2] = vA.z; vv[3] = vA.w;
        vv[4] = vB.x; vv[5] = vB.y; vv[6] = vB.z; vv[7] = vB.w;
#pragma unroll
        for (int j = 0; j < 8; ++j) {
            float s0 = RCP(fmaf(et[j], ecr[0][j], 1.0f));
            float s1 = RCP(fmaf(et[j], ecr[1][j], 1.0f));
            float s2 = RCP(fmaf(et[j], ecr[2][j], 1.0f));
            float s3 = RCP(fmaf(et[j], ecr[3][j], 1.0f));
            p0 = fmaf(vv[j], s0, p0);
            p1 = fmaf(vv[j], s1, p1);
            p2 = fmaf(vv[j], s2, p2);
            p3 = fmaf(vv[j], s3, p3);
        }
    }

    // ---- phase 7: softmax across lanes (lane = t), write bf16 weights ----
    float xs4[4] = { -2.0f * p0, -2.0f * p1, -2.0f * p2, -2.0f * p3 };
#pragma unroll
    for (int r = 0; r < 4; ++r) {
        float x = xs4[r];
        float mx = x;
#pragma unroll
        for (int m = 1; m < 64; m <<= 1) mx = fmaxf(mx, __shfl_xor(mx, m, 64));
        float e = EXP2(L2E * (x - mx));
        float s = e;
#pragma unroll
        for (int m = 1; m < 64; m <<= 1) s += __shfl_xor(s, m, 64);
        wgtb[(wv * 4 + r) * 72 + lane] = (__bf16)(e * RCP(s));
    }
    __syncthreads();

    // ---- phase 8: emb MFMA. wave = (row-group rg4 = wv>>2) x (col-group cg = wv&3) ----
    int rg4 = wv >> 2, cg = wv & 3;
    f32x4 em[4] = {};
#pragma unroll
    for (int kb = 0; kb < 2; ++kb) {
        bf16x8 afrag = *reinterpret_cast<const bf16x8*>(&wgtb[(rg4 * 16 + lan15) * 72 + kb * 32 + klo]);
#pragma unroll
        for (int nt = 0; nt < 4; ++nt) {
            int n = cg * 64 + nt * 16 + lan15;
            bf16x8 bfrag = *reinterpret_cast<const bf16x8*>(&histT[n * T_ + kb * 32 + klo]);
            em[nt] = __builtin_amdgcn_mfma_f32_16x16x32_bf16(afrag, bfrag, em[nt], 0, 0, 0);
        }
    }
    // C layout: col = lan15 (n), row = kg*4 + rg within the 16-row group
#pragma unroll
    for (int rg = 0; rg < 4; ++rg) {
        int row = rg4 * 16 + kg * 4 + rg;
        size_t grow = (size_t)(b0 + row);
        bool m = get_mask(maskp, mflag, (int)grow);
#pragma unroll
        for (int nt = 0; nt < 4; ++nt) {
            int d2 = cg * 64 + nt * 16 + lan15;
            float av = accum[grow * D_ + d2];
            out_emb[grow * D_ + d2] = m ? fmaf(av, DECAY_, em[nt][rg]) : av;
        }
    }
}

extern "C" void kernel_launch(void* const* d_in, const int* in_sizes, int n_in,
                              void* d_out, int out_size, void* d_ws, size_t ws_size,
                              hipStream_t stream) {
    const float* features = (const float*)d_in[0];
    const float* h        = (const float*)d_in[1];
    const float* accum    = (const float*)d_in[2];
    const void*  maskp    = d_in[3];
    const float* tokens   = (const float*)d_in[4];
    const float* Wih      = (const float*)d_in[5];
    const float* Whh      = (const float*)d_in[6];
    const float* bih      = (const float*)d_in[7];
    const float* bhh      = (const float*)d_in[8];
    const float* Wh       = (const float*)d_in[9];
    const float* bh       = (const float*)d_in[10];
    const float* Wc       = (const float*)d_in[11];
    const float* bc       = (const float*)d_in[12];
    const float* v        = (const float*)d_in[13];
    // d_in[14] = bv : softmax-invariant, unused

    float* out = (float*)d_out;  // [B*D] emb_out, then [B*D] h_out

    __bf16* Wihb  = (__bf16*)d_ws;                  // 768*128
    __bf16* Whhb  = Wihb + 768 * 128;               // 768*256
    __bf16* Wcb   = Whhb + 768 * 256;               // 256*256
    __bf16* histT = Wcb + 256 * 256;                // 256*64 bf16 (transposed hist)
    __bf16* etp   = histT + 256 * 64;               // 64*256 bf16 (packed exp2 of tokp~)
    int*    mflag = (int*)(etp + 64 * 256);

    hipLaunchKernelGGL(convert_prep, dim3(417), dim3(256), 0, stream,
                       Wih, Whh, Wc, Wihb, Whhb, Wcb,
                       (const unsigned int*)maskp, mflag,
                       tokens, Wh, bh, histT, etp);
    hipLaunchKernelGGL(gru_attn, dim3(B_ / 64), dim3(1024), 0, stream,
                       features, h, maskp, mflag, Wihb, Whhb, Wcb, bih, bhh, bc,
                       (const unsigned short*)etp, histT, v, accum,
                       out + (size_t)B_ * D_, out);
}

// Round 23
// 84.664 us; speedup vs baseline: 1.0244x; 1.0244x over previous
//
#include <hip/hip_runtime.h>
#include <hip/hip_bf16.h>

#define B_ 16384
#define F_ 128
#define D_ 256
#define A_ 256
#define T_ 64
#define DECAY_ 0.9f
#define SCALE2 2.885390081777927f   // 2*log2(e)
#define L2E    1.4426950408889634f  // log2(e)

typedef __attribute__((ext_vector_type(8))) __bf16 bf16x8;
typedef __attribute__((ext_vector_type(4))) float f32x4;

#if __has_builtin(__builtin_amdgcn_exp2f)
#define EXP2(x) __builtin_amdgcn_exp2f(x)
#else
#define EXP2(x) exp2f(x)
#endif
#define RCP(x) __builtin_amdgcn_rcpf(x)

__device__ __forceinline__ float tanh2(float x) {
    float e = EXP2(SCALE2 * x);
    return 1.0f - 2.0f * RCP(e + 1.0f);
}
__device__ __forceinline__ float sigmoid2(float x) {
    float e = EXP2(-L2E * x);
    return RCP(1.0f + e);
}
__device__ __forceinline__ bool get_mask(const void* mp, int mflag, int row) {
    if (mflag) return ((const unsigned char*)mp)[row] != 0;
    return ((const int*)mp)[row] != 0;
}
__device__ __forceinline__ unsigned short bfbits(float f) {
    __bf16 h = (__bf16)f;
    return __builtin_bit_cast(unsigned short, h);
}
__device__ __forceinline__ float bits2f(unsigned short u) {
    return __builtin_bit_cast(float, ((unsigned)u) << 16);
}

// ---- merged front kernel: blocks 0-351 convert weights, 352 = mask probe, 353-416 = prep ----
// prep: histT[d][t] = bf16(tanh(tokens)) [256][64]; etp = bf16(exp2(SCALE2*tok_proj)) packed
// etp layout: element (a,t) at (a>>2)*256 + t*4 + (a&3)
__global__ __launch_bounds__(256) void convert_prep(
    const float* Wih, const float* Whh, const float* Wc,
    __bf16* Wihb, __bf16* Whhb, __bf16* Wcb,
    const unsigned int* mword, int* flag,
    const float* tokens, const float* Wh, const float* bh,
    __bf16* histT, __bf16* etp)
{
    __shared__ float hrow[D_];
    const int n1 = 768 * 128, n2 = n1 + 768 * 256, n3 = n2 + 256 * 256;
    int bid = blockIdx.x;
    int tid = threadIdx.x;

    if (bid >= 353) {               // ---- prep path: t = bid - 353 ----
        int t = bid - 353;
        float hv = tanh2(tokens[t * D_ + tid]);
        hrow[tid] = hv;
        histT[tid * T_ + t] = (__bf16)hv;   // transposed for MFMA B-frag
        __syncthreads();
        float acc = bh[tid];
        const float* wr = &Wh[tid * D_];
        for (int d = 0; d < D_; d++) acc += hrow[d] * wr[d];
        etp[(tid >> 2) * 256 + t * 4 + (tid & 3)] = (__bf16)EXP2(acc * SCALE2);
        return;
    }
    if (bid == 352) {               // ---- mask probe: packed bools -> some 4B word >1 ----
        __shared__ int f;
        if (tid == 0) f = 0;
        __syncthreads();
        int any = 0;
        for (int i = tid; i < B_ / 4; i += 256) any |= (mword[i] > 1u) ? 1 : 0;
        if (any) atomicOr(&f, 1);
        __syncthreads();
        if (tid == 0) flag[0] = f;
        return;
    }
    int i = (bid * 256 + tid) * 4;  // ---- weight conversion ----
    if (i < n1) {
#pragma unroll
        for (int j = 0; j < 4; ++j) Wihb[i + j] = (__bf16)Wih[i + j];
    } else if (i < n2) {
        int k = i - n1;
#pragma unroll
        for (int j = 0; j < 4; ++j) Whhb[k + j] = (__bf16)Whh[k + j];
    } else if (i < n3) {
        int k = i - n2;
#pragma unroll
        for (int j = 0; j < 4; ++j) Wcb[k + j] = (__bf16)Wc[k + j];
    }
}

// ---- gru4 (r15-r21 proven): 64 rows x 256 cols/block, 1024 thr, in-place Hn overlay ----
// ec output stored bf16 (halves ec store traffic)
#define XS 392   // shorts/row: 384 + 8 pad (f[0:128] | h->hn[128:384])
__global__ __launch_bounds__(1024) void gru_fused(
    const float* __restrict__ features, const float* __restrict__ h,
    const void* maskp, const int* __restrict__ mflagp,
    const __bf16* __restrict__ Wihb, const __bf16* __restrict__ Whhb, const __bf16* __restrict__ Wcb,
    const float* __restrict__ b_ih, const float* __restrict__ b_hh, const float* __restrict__ bcp,
    float* __restrict__ hout, __bf16* __restrict__ ecb)
{
    __shared__ __bf16 Xs[64 * XS];   // 50176 B
    int tid = threadIdx.x;
    int b0 = blockIdx.x * 64;
    int wv = tid >> 6, lane = tid & 63;   // wv in [0,16)
    int lan15 = lane & 15, kg = lane >> 4;
    int klo = kg * 8;
    int d = wv * 16 + lan15;              // this thread's gate column
    int mflag = mflagp[0];

#pragma unroll
    for (int it = 0; it < 2; ++it) {
        int idx = (it * 1024 + tid) * 4;
        int r = idx >> 7, c = idx & 127;
        float4 vv = *(const float4*)&features[(size_t)(b0 + r) * F_ + c];
        ushort4 w = { bfbits(vv.x), bfbits(vv.y), bfbits(vv.z), bfbits(vv.w) };
        *reinterpret_cast<ushort4*>(&Xs[r * XS + c]) = w;
    }
#pragma unroll
    for (int it = 0; it < 4; ++it) {
        int idx = (it * 1024 + tid) * 4;
        int r = idx >> 8, c = idx & 255;
        float4 vv = *(const float4*)&h[(size_t)(b0 + r) * D_ + c];
        ushort4 w = { bfbits(vv.x), bfbits(vv.y), bfbits(vv.z), bfbits(vv.w) };
        *reinterpret_cast<ushort4*>(&Xs[r * XS + 128 + c]) = w;
    }
    float brv = b_ih[d] + b_hh[d];
    float bzv = b_ih[256 + d] + b_hh[256 + d];
    float biv = b_ih[512 + d];
    float bhv = b_hh[512 + d];
    float bcv = bcp[d];
    __syncthreads();

    f32x4 ar[4] = {}, az[4] = {}, ai[4] = {}, ah[4] = {};

#pragma unroll
    for (int kb = 0; kb < 4; ++kb) {
        bf16x8 a[4];
#pragma unroll
        for (int rf = 0; rf < 4; ++rf)
            a[rf] = *reinterpret_cast<const bf16x8*>(&Xs[(rf * 16 + lan15) * XS + kb * 32 + klo]);
        const __bf16* p = Wihb + (size_t)d * F_ + kb * 32 + klo;
        bf16x8 br = *reinterpret_cast<const bf16x8*>(p);
        bf16x8 bz = *reinterpret_cast<const bf16x8*>(p + 256 * F_);
        bf16x8 bn = *reinterpret_cast<const bf16x8*>(p + 512 * F_);
#pragma unroll
        for (int rf = 0; rf < 4; ++rf) {
            ar[rf] = __builtin_amdgcn_mfma_f32_16x16x32_bf16(a[rf], br, ar[rf], 0, 0, 0);
            az[rf] = __builtin_amdgcn_mfma_f32_16x16x32_bf16(a[rf], bz, az[rf], 0, 0, 0);
            ai[rf] = __builtin_amdgcn_mfma_f32_16x16x32_bf16(a[rf], bn, ai[rf], 0, 0, 0);
        }
    }
#pragma unroll
    for (int kb = 0; kb < 8; ++kb) {
        bf16x8 a[4];
#pragma unroll
        for (int rf = 0; rf < 4; ++rf)
            a[rf] = *reinterpret_cast<const bf16x8*>(&Xs[(rf * 16 + lan15) * XS + 128 + kb * 32 + klo]);
        const __bf16* p = Whhb + (size_t)d * D_ + kb * 32 + klo;
        bf16x8 br = *reinterpret_cast<const bf16x8*>(p);
        bf16x8 bz = *reinterpret_cast<const bf16x8*>(p + 256 * D_);
        bf16x8 bn = *reinterpret_cast<const bf16x8*>(p + 512 * D_);
#pragma unroll
        for (int rf = 0; rf < 4; ++rf) {
            ar[rf] = __builtin_amdgcn_mfma_f32_16x16x32_bf16(a[rf], br, ar[rf], 0, 0, 0);
            az[rf] = __builtin_amdgcn_mfma_f32_16x16x32_bf16(a[rf], bz, az[rf], 0, 0, 0);
            ah[rf] = __builtin_amdgcn_mfma_f32_16x16x32_bf16(a[rf], bn, ah[rf], 0, 0, 0);
        }
    }

    __syncthreads();   // all waves done reading old h before any overlay write

#pragma unroll
    for (int rf = 0; rf < 4; ++rf) {
#pragma unroll
        for (int rg = 0; rg < 4; ++rg) {
            int row = rf * 16 + kg * 4 + rg;
            int grow = b0 + row;
            float hv = (float)Xs[row * XS + 128 + d];
            float rv = sigmoid2(ar[rf][rg] + brv);
            float zv = sigmoid2(az[rf][rg] + bzv);
            float nv = tanh2(ai[rf][rg] + biv + rv * (ah[rf][rg] + bhv));
            float hn = (1.0f - zv) * nv + zv * hv;
            Xs[row * XS + 128 + d] = (__bf16)hn;   // in-place: each (row,d) owned by one thread
            bool m = get_mask(maskp, mflag, grow);
            hout[(size_t)grow * D_ + d] = m ? hn : hv;
        }
    }
    __syncthreads();

    f32x4 ac[4] = {};
#pragma unroll
    for (int kb = 0; kb < 8; ++kb) {
        bf16x8 b = *reinterpret_cast<const bf16x8*>(&Wcb[(size_t)d * D_ + kb * 32 + klo]);
#pragma unroll
        for (int rf = 0; rf < 4; ++rf) {
            bf16x8 a = *reinterpret_cast<const bf16x8*>(&Xs[(rf * 16 + lan15) * XS + 128 + kb * 32 + klo]);
            ac[rf] = __builtin_amdgcn_mfma_f32_16x16x32_bf16(a, b, ac[rf], 0, 0, 0);
        }
    }
#pragma unroll
    for (int rf = 0; rf < 4; ++rf) {
#pragma unroll
        for (int rg = 0; rg < 4; ++rg) {
            int row = rf * 16 + kg * 4 + rg;
            ecb[(size_t)(b0 + row) * A_ + d] = (__bf16)EXP2((ac[rf][rg] + bcv) * SCALE2);
        }
    }
}

// ---- attention v11b (r21 proven): 16 rows/block, 4 rows/wave, bf16 ec -> f32 LDS, MFMA emb ----
__global__ __launch_bounds__(256) void attn11(
    const __bf16* __restrict__ ecb_g, const unsigned short* __restrict__ etp,
    const __bf16* __restrict__ histT, const float* __restrict__ v,
    const float* __restrict__ accum, const void* maskp, const int* __restrict__ mflagp,
    float* __restrict__ out_emb)
{
    __shared__ float ecs[16 * A_];     // 16KB: ec rows (f32) for this block
    __shared__ float vs[A_];           // 1KB
    __shared__ __bf16 wgtb[16 * 72];   // 2.25KB: softmax weights (all 16 rows valid)
    int tid = threadIdx.x;
    int b0 = blockIdx.x * 16;
    int wv = tid >> 6, lane = tid & 63;   // lane = t
    int mflag = mflagp[0];

    // stage ec (16 rows x 256, bf16 -> f32) and v
    {
        const bf16x8* src = (const bf16x8*)(ecb_g + (size_t)b0 * A_);   // 512 bf16x8
#pragma unroll
        for (int it = 0; it < 2; ++it) {
            int e = it * 256 + tid;
            bf16x8 w8 = src[e];
            float4 lo, hi;
            lo.x = (float)w8[0]; lo.y = (float)w8[1]; lo.z = (float)w8[2]; lo.w = (float)w8[3];
            hi.x = (float)w8[4]; hi.y = (float)w8[5]; hi.z = (float)w8[6]; hi.w = (float)w8[7];
            *(float4*)&ecs[e * 8] = lo;
            *(float4*)&ecs[e * 8 + 4] = hi;
        }
        if (tid < 64) ((float4*)vs)[tid] = ((const float4*)v)[tid];
    }
    __syncthreads();

    const float* ecb = ecs + (size_t)(wv * 4) * A_;

    float p0 = 0.f, p1 = 0.f, p2 = 0.f, p3 = 0.f;
#pragma unroll 4
    for (int ch = 0; ch < 32; ++ch) {
        int a0 = ch * 8;
        const unsigned short* ep = etp + (a0 >> 2) * 256 + lane * 4;
        uint2 q0 = *(const uint2*)ep;            // et for a0..a0+3 at this lane's t
        uint2 q1 = *(const uint2*)(ep + 256);    // a0+4..a0+7
        float4 vA = *(const float4*)&vs[a0];
        float4 vB = *(const float4*)&vs[a0 + 4];
        float ecr[4][8];
#pragma unroll
        for (int r = 0; r < 4; ++r) {
            float4 ca = *(const float4*)&ecb[r * A_ + a0];
            float4 cb = *(const float4*)&ecb[r * A_ + a0 + 4];
            ecr[r][0] = ca.x; ecr[r][1] = ca.y; ecr[r][2] = ca.z; ecr[r][3] = ca.w;
            ecr[r][4] = cb.x; ecr[r][5] = cb.y; ecr[r][6] = cb.z; ecr[r][7] = cb.w;
        }
        float et[8];
        et[0] = __builtin_bit_cast(float, q0.x << 16);
        et[1] = __builtin_bit_cast(float, q0.x & 0xffff0000u);
        et[2] = __builtin_bit_cast(float, q0.y << 16);
        et[3] = __builtin_bit_cast(float, q0.y & 0xffff0000u);
        et[4] = __builtin_bit_cast(float, q1.x << 16);
        et[5] = __builtin_bit_cast(float, q1.x & 0xffff0000u);
        et[6] = __builtin_bit_cast(float, q1.y << 16);
        et[7] = __builtin_bit_cast(float, q1.y & 0xffff0000u);
        float vv[8];
        vv[0] = vA.x; vv[1] = vA.y; vv[2] = vA.z; vv[3] = vA.w;
        vv[4] = vB.x; vv[5] = vB.y; vv[6] = vB.z; vv[7] = vB.w;
#pragma unroll
        for (int j = 0; j < 8; ++j) {
            float s0 = RCP(fmaf(et[j], ecr[0][j], 1.0f));
            float s1 = RCP(fmaf(et[j], ecr[1][j], 1.0f));
            float s2 = RCP(fmaf(et[j], ecr[2][j], 1.0f));
            float s3 = RCP(fmaf(et[j], ecr[3][j], 1.0f));
            p0 = fmaf(vv[j], s0, p0);
            p1 = fmaf(vv[j], s1, p1);
            p2 = fmaf(vv[j], s2, p2);
            p3 = fmaf(vv[j], s3, p3);
        }
    }

    // softmax across lanes (lane = t); 4 rows/wave; write bf16 weights to wgtb
    float xs[4] = { -2.0f * p0, -2.0f * p1, -2.0f * p2, -2.0f * p3 };
#pragma unroll
    for (int r = 0; r < 4; ++r) {
        float x = xs[r];
        float mx = x;
#pragma unroll
        for (int m = 1; m < 64; m <<= 1) mx = fmaxf(mx, __shfl_xor(mx, m, 64));
        float e = EXP2(L2E * (x - mx));
        float s = e;
#pragma unroll
        for (int m = 1; m < 64; m <<= 1) s += __shfl_xor(s, m, 64);
        wgtb[(wv * 4 + r) * 72 + lane] = (__bf16)(e * RCP(s));
    }
    __syncthreads();

    // emb = wgt[16,64] @ hist[64,256] via MFMA: wave wv owns cols [wv*64, wv*64+64)
    int lan15 = lane & 15, kg = lane >> 4, klo = kg * 8;
    f32x4 em[4] = {};
#pragma unroll
    for (int kb = 0; kb < 2; ++kb) {
        bf16x8 afrag = *reinterpret_cast<const bf16x8*>(&wgtb[lan15 * 72 + kb * 32 + klo]);
#pragma unroll
        for (int nt = 0; nt < 4; ++nt) {
            int n = wv * 64 + nt * 16 + lan15;
            bf16x8 bfrag = *reinterpret_cast<const bf16x8*>(&histT[n * T_ + kb * 32 + klo]);
            em[nt] = __builtin_amdgcn_mfma_f32_16x16x32_bf16(afrag, bfrag, em[nt], 0, 0, 0);
        }
    }
    // C layout: col = lan15 (n), row = kg*4 + rg; all 16 rows valid
#pragma unroll
    for (int rg = 0; rg < 4; ++rg) {
        int row = kg * 4 + rg;
        size_t grow = (size_t)(b0 + row);
        bool m = get_mask(maskp, mflag, (int)grow);
#pragma unroll
        for (int nt = 0; nt < 4; ++nt) {
            int d = wv * 64 + nt * 16 + lan15;
            float av = accum[grow * D_ + d];
            out_emb[grow * D_ + d] = m ? fmaf(av, DECAY_, em[nt][rg]) : av;
        }
    }
}

extern "C" void kernel_launch(void* const* d_in, const int* in_sizes, int n_in,
                              void* d_out, int out_size, void* d_ws, size_t ws_size,
                              hipStream_t stream) {
    const float* features = (const float*)d_in[0];
    const float* h        = (const float*)d_in[1];
    const float* accum    = (const float*)d_in[2];
    const void*  maskp    = d_in[3];
    const float* tokens   = (const float*)d_in[4];
    const float* Wih      = (const float*)d_in[5];
    const float* Whh      = (const float*)d_in[6];
    const float* bih      = (const float*)d_in[7];
    const float* bhh      = (const float*)d_in[8];
    const float* Wh       = (const float*)d_in[9];
    const float* bh       = (const float*)d_in[10];
    const float* Wc       = (const float*)d_in[11];
    const float* bc       = (const float*)d_in[12];
    const float* v        = (const float*)d_in[13];
    // d_in[14] = bv : softmax-invariant, unused

    float* out = (float*)d_out;  // [B*D] emb_out, then [B*D] h_out

    __bf16* Wihb  = (__bf16*)d_ws;                  // 768*128
    __bf16* Whhb  = Wihb + 768 * 128;               // 768*256
    __bf16* Wcb   = Whhb + 768 * 256;               // 256*256
    __bf16* histT = Wcb + 256 * 256;                // 256*64 bf16 (transposed hist)
    __bf16* etp   = histT + 256 * 64;               // 64*256 bf16 (packed exp2 of tokp~)
    __bf16* ecb   = etp + 64 * 256;                 // B*256 bf16 (exp2 of ctx~)
    int*    mflag = (int*)(ecb + (size_t)B_ * D_);

    hipLaunchKernelGGL(convert_prep, dim3(417), dim3(256), 0, stream,
                       Wih, Whh, Wc, Wihb, Whhb, Wcb,
                       (const unsigned int*)maskp, mflag,
                       tokens, Wh, bh, histT, etp);
    hipLaunchKernelGGL(gru_fused, dim3(B_ / 64), dim3(1024), 0, stream,
                       features, h, maskp, mflag, Wihb, Whhb, Wcb, bih, bhh, bc,
                       out + (size_t)B_ * D_, ecb);
    hipLaunchKernelGGL(attn11, dim3(B_ / 16), dim3(256), 0, stream,
                       ecb, (const unsigned short*)etp, histT, v, accum, maskp, mflag, out);
}